// Round 2
// baseline (266.785 us; speedup 1.0000x reference)
//
#include <hip/hip_runtime.h>
#include <math.h>

#define NB 8
#define NH 3
#define NBH 24
#define NP 4096
#define BLK 256
#define RPB 64             // rows per block (2 row-waves x 32; 2 col-half waves)
#define ROWBLKS (NP / RPB) // 64

typedef _Float16 half4 __attribute__((ext_vector_type(4)));
typedef _Float16 half8 __attribute__((ext_vector_type(8)));
typedef float floatx16 __attribute__((ext_vector_type(16)));

// Forced v_min3_f32 (3-input min; no -ffast-math so compiler won't fuse).
#define MIN3(r, a, b) asm("v_min3_f32 %0, %0, %1, %2" : "+v"(r) : "v"(a), "v"(bb_##a), "v"(b))
#undef MIN3
#define MIN3(r, a, b) asm("v_min3_f32 %0, %0, %1, %2" : "+v"(r) : "v"(a), "v"(b))

// Native gfx950 x16 MFMA via inline asm, all-VGPR (no AGPR parking).
#define MFMA16(d, a, bb, c) \
    asm("v_mfma_f32_32x32x16_f16 %0, %1, %2, %3" : "=&v"(d) : "v"(a), "v"(bb), "v"(c))

// Prep: for each (b,h), reflect all 4096 points and pack per-column
// [-2c0,-2c1,-2c2,csq] as 4xf16 into the workspace (24 x 32KB = 768KB,
// L2-resident). Done ONCE per (b,h) instead of once per rowblock (32x
// redundancy removed from the hot kernel). Block 0 wave 3 also computes
// the regularizer and plain-stores out[0] (chamfer atomicAdds after).
__global__ void __launch_bounds__(256) prep_kernel(const float* __restrict__ pts,
                                                   const float* __restrict__ planes,
                                                   _Float16* __restrict__ qg,
                                                   float* __restrict__ out) {
    const int tid = threadIdx.x;
    const int bh  = blockIdx.x >> 2;      // 96 blocks, 4 per (b,h)
    const int b   = bh / NH;

    const float* pl = planes + bh * 4;
    float n0 = pl[0], n1 = pl[1], n2 = pl[2], off = pl[3];
    float inv = 1.0f / sqrtf(n0 * n0 + n1 * n1 + n2 * n2);
    n0 *= inv; n1 *= inv; n2 *= inv;

    const float* bp = pts + (size_t)b * NP * 3;
    const int base = (blockIdx.x & 3) * 1024 + tid;
    #pragma unroll
    for (int k = 0; k < 4; ++k) {
        const int i = base + k * 256;
        float y0 = bp[i * 3 + 0], y1 = bp[i * 3 + 1], y2 = bp[i * 3 + 2];
        float t = 2.0f * (n0 * y0 + n1 * y1 + n2 * y2 + off);
        y0 -= t * n0; y1 -= t * n1; y2 -= t * n2;
        float csq = y0 * y0 + y1 * y1 + y2 * y2;
        half4 q = { (_Float16)(-2.0f * y0), (_Float16)(-2.0f * y1),
                    (_Float16)(-2.0f * y2), (_Float16)csq };
        *(half4*)(qg + ((size_t)bh * NP + i) * 4) = q;
    }

    if (blockIdx.x == 0 && tid >= 192) {   // reg loss on wave 3
        const int l = tid - 192;
        float r = 0.0f;
        if (l < NB) {
            float n[NH][3];
            for (int hh = 0; hh < NH; ++hh) {
                const float* p2 = planes + (l * NH + hh) * 4;
                float a0 = p2[0], a1 = p2[1], a2 = p2[2];
                float iv = 1.0f / sqrtf(a0 * a0 + a1 * a1 + a2 * a2);
                n[hh][0] = a0 * iv; n[hh][1] = a1 * iv; n[hh][2] = a2 * iv;
            }
            float fro = 0.0f;
            for (int i = 0; i < NH; ++i)
                for (int j = 0; j < NH; ++j) {
                    float d = n[i][0] * n[j][0] + n[i][1] * n[j][1] + n[i][2] * n[j][2]
                              - (i == j ? 1.0f : 0.0f);
                    fro += d * d;
                }
            r = 25.0f * sqrtf(fro);
        }
        for (int o = 32; o; o >>= 1) r += __shfl_down(r, o);
        if (l == 0) out[0] = r;
    }
}

// SYMMETRY: the reflection is an affine isometric involution, so the
// (x vs reflected-x) distance matrix is symmetric => cham_x == cham_y;
// compute row-mins once and double.
//
// v2 structure: NO 32KB LDS staging — B fragments (raw half8 = two packed
// columns, even col k=0..3 / odd col k=4..7) stream straight from the
// prep table in L2 via global_load_dwordx4 (upper half-wave reads the
// same lines: broadcast, no extra traffic). Each block = 64 rows; its 4
// waves = 2 row-groups x 2 column-halves (32 supertiles each), so the
// grid is 64x24 = 1536 blocks = 6 blocks/CU = 75% occupancy (vs 22.7%):
// the extra TLP hides MFMA->min3 and load latency the old 3-wave/SIMD
// version couldn't. Col-halves min-combine via 512B LDS; clamp AFTER the
// combine (max(min(a,b),0) — monotone, exact). 4-buffer load pipeline
// unchanged: loads ~2 lines ahead of their MFMA, min3 ~2 lines behind.
__global__ void __launch_bounds__(BLK, 6) chamfer_mfma(const float* __restrict__ pts,
                                                       const _Float16* __restrict__ qg,
                                                       float* __restrict__ out) {
    __shared__ float rowmin[2][RPB];

    const int tid  = threadIdx.x;
    const int lane = tid & 63;
    const int wave = tid >> 6;
    const int bh   = blockIdx.y;
    const int b    = bh / NH;
    const int rw   = wave & 1;   // row group
    const int cw   = wave >> 1;  // column half
    const int h    = lane >> 5;

    const float* bp = pts + (size_t)b * NP * 3;

    // A fragments: rows = ORIGINAL points. All lanes load their row (dup
    // across halves) so rsq is shuffle-able without LDS/barrier.
    const int rlocal = rw * 32 + (lane & 31);
    const int row = blockIdx.x * RPB + rlocal;
    float a0 = bp[row * 3 + 0], a1 = bp[row * 3 + 1], a2 = bp[row * 3 + 2];
    float rsq = a0 * a0 + a1 * a1 + a2 * a2;
    half8 Aev = {0, 0, 0, 0, 0, 0, 0, 0};
    half8 Aod = {0, 0, 0, 0, 0, 0, 0, 0};
    if (lane < 32) {
        Aev[0] = (_Float16)a0; Aev[1] = (_Float16)a1;
        Aev[2] = (_Float16)a2; Aev[3] = (_Float16)1.0f;
        Aod[4] = (_Float16)a0; Aod[5] = (_Float16)a1;
        Aod[6] = (_Float16)a2; Aod[7] = (_Float16)1.0f;
    }

    // C fragment: rsq per output row (C/D: col=lane&31, row=(j&3)+8*(j>>2)+4*h)
    floatx16 crsq;
    #pragma unroll
    for (int j = 0; j < 16; ++j)
        crsq[j] = __shfl(rsq, (j & 3) + 8 * (j >> 2) + 4 * h);

    float rm[16];
    #pragma unroll
    for (int j = 0; j < 16; ++j) rm[j] = 1e30f;

    // supertile u (64 cols): lane reads cols u*64 + {2l, 2l+1} as one dwordx4
    const _Float16* bcol = qg + (size_t)bh * NP * 4 + (lane & 31) * 8;
    const int U0 = cw * 32;
    #define LD(u) (*(const half8*)(bcol + (size_t)(u) * 256))

    half8 c0 = LD(U0), c1 = LD(U0 + 1), c2 = LD(U0 + 2), c3 = LD(U0 + 3);
    floatx16 dA0, dA1, dB0, dB1;
    MFMA16(dA0, Aev, c0, crsq);  MFMA16(dA1, Aod, c0, crsq);   // st U0
    MFMA16(dB0, Aev, c1, crsq);  MFMA16(dB1, Aod, c1, crsq);   // st U0+1

    #pragma unroll 1
    for (int u = U0 + 4; u <= U0 + 28; u += 4) {
        c0 = LD(u);
        #pragma unroll
        for (int j = 0; j < 16; ++j) MIN3(rm[j], dA0[j], dA1[j]);   // st u-4
        MFMA16(dA0, Aev, c2, crsq);  MFMA16(dA1, Aod, c2, crsq);    // st u-2
        c1 = LD(u + 1);
        #pragma unroll
        for (int j = 0; j < 16; ++j) MIN3(rm[j], dB0[j], dB1[j]);   // st u-3
        MFMA16(dB0, Aev, c3, crsq);  MFMA16(dB1, Aod, c3, crsq);    // st u-1
        c2 = LD(u + 2);
        #pragma unroll
        for (int j = 0; j < 16; ++j) MIN3(rm[j], dA0[j], dA1[j]);   // st u-2
        MFMA16(dA0, Aev, c0, crsq);  MFMA16(dA1, Aod, c0, crsq);    // st u
        c3 = LD(u + 3);
        #pragma unroll
        for (int j = 0; j < 16; ++j) MIN3(rm[j], dB0[j], dB1[j]);   // st u-1
        MFMA16(dB0, Aev, c1, crsq);  MFMA16(dB1, Aod, c1, crsq);    // st u+1
    }
    {   // epilogue: st U0+30, U0+31 issue + drain
        #pragma unroll
        for (int j = 0; j < 16; ++j) MIN3(rm[j], dA0[j], dA1[j]);   // st U0+28
        MFMA16(dA0, Aev, c2, crsq);  MFMA16(dA1, Aod, c2, crsq);    // st U0+30
        #pragma unroll
        for (int j = 0; j < 16; ++j) MIN3(rm[j], dB0[j], dB1[j]);   // st U0+29
        MFMA16(dB0, Aev, c3, crsq);  MFMA16(dB1, Aod, c3, crsq);    // st U0+31
        #pragma unroll
        for (int j = 0; j < 16; ++j) MIN3(rm[j], dA0[j], dA1[j]);   // st U0+30
        #pragma unroll
        for (int j = 0; j < 16; ++j) MIN3(rm[j], dB0[j], dB1[j]);   // st U0+31
    }
    #undef LD

    // min across the 32 lanes sharing each row (within this col-half)
    #pragma unroll
    for (int j = 0; j < 16; ++j) {
        float v = rm[j];
        v = fminf(v, __shfl_xor(v, 1));
        v = fminf(v, __shfl_xor(v, 2));
        v = fminf(v, __shfl_xor(v, 4));
        v = fminf(v, __shfl_xor(v, 8));
        v = fminf(v, __shfl_xor(v, 16));
        rm[j] = v;
    }

    // publish per-row partial mins (one lane per 32-group; constant j idx
    // only — runtime-indexing rm[] would spill to scratch)
    if ((lane & 31) == 0) {
        #pragma unroll
        for (int j = 0; j < 16; ++j)
            rowmin[cw][rw * 32 + (j & 3) + 8 * (j >> 2) + 4 * h] = rm[j];
    }
    __syncthreads();

    // combine col-halves, clamp, sum 64 rows, one atomic per block
    if (tid < RPB) {
        float v = fmaxf(fminf(rowmin[0][tid], rowmin[1][tid]), 0.0f);
        #pragma unroll
        for (int o = 32; o; o >>= 1) v += __shfl_down(v, o);
        if (tid == 0) atomicAdd(out, v * (2.0f / (float)(NB * NP)));
    }
}

extern "C" void kernel_launch(void* const* d_in, const int* in_sizes, int n_in,
                              void* d_out, int out_size, void* d_ws, size_t ws_size,
                              hipStream_t stream) {
    const float* planes = (const float*)d_in[0];  // (8,3,4) fp32
    const float* pts    = (const float*)d_in[1];  // (8,4096,3) fp32
    float* out          = (float*)d_out;
    _Float16* qg        = (_Float16*)d_ws;        // needs 24*4096*8 = 768 KB

    prep_kernel<<<96, 256, 0, stream>>>(pts, planes, qg, out);

    dim3 grid(ROWBLKS, NBH);
    chamfer_mfma<<<grid, BLK, 0, stream>>>(pts, qg, out);
}

// Round 3
// 193.952 us; speedup vs baseline: 1.3755x; 1.3755x over previous
//
#include <hip/hip_runtime.h>
#include <math.h>

#define NB 8
#define NH 3
#define NBH 24
#define NP 4096
#define BLK 256
#define RPB 64             // rows per block (2 row-waves x 32; 2 col-half waves)
#define ROWBLKS (NP / RPB) // 64

typedef _Float16 half4 __attribute__((ext_vector_type(4)));
typedef _Float16 half8 __attribute__((ext_vector_type(8)));
typedef float floatx16 __attribute__((ext_vector_type(16)));

// Forced v_min3_f32 (3-input min; no -ffast-math so compiler won't fuse).
#define MIN3(r, a, b) asm("v_min3_f32 %0, %0, %1, %2" : "+v"(r) : "v"(a), "v"(b))

// Native gfx950 x16 MFMA via inline asm, all-VGPR (no AGPR parking).
#define MFMA16(d, a, bb, c) \
    asm("v_mfma_f32_32x32x16_f16 %0, %1, %2, %3" : "=&v"(d) : "v"(a), "v"(bb), "v"(c))

// Prep: for each (b,h), reflect all 4096 points and pack per-column
// [-2c0,-2c1,-2c2,csq] as 4xf16 into the workspace (24 x 32KB = 768KB,
// L2-resident; harness ws is ~268MB so plenty). Done ONCE per (b,h)
// instead of once per rowblock. Block 0 wave 3 also computes the
// regularizer and plain-stores out[0] (chamfer atomicAdds after).
__global__ void __launch_bounds__(256) prep_kernel(const float* __restrict__ pts,
                                                   const float* __restrict__ planes,
                                                   _Float16* __restrict__ qg,
                                                   float* __restrict__ out) {
    const int tid = threadIdx.x;
    const int bh  = blockIdx.x >> 2;      // 96 blocks, 4 per (b,h)
    const int b   = bh / NH;

    const float* pl = planes + bh * 4;
    float n0 = pl[0], n1 = pl[1], n2 = pl[2], off = pl[3];
    float inv = 1.0f / sqrtf(n0 * n0 + n1 * n1 + n2 * n2);
    n0 *= inv; n1 *= inv; n2 *= inv;

    const float* bp = pts + (size_t)b * NP * 3;
    const int base = (blockIdx.x & 3) * 1024 + tid;
    #pragma unroll
    for (int k = 0; k < 4; ++k) {
        const int i = base + k * 256;
        float y0 = bp[i * 3 + 0], y1 = bp[i * 3 + 1], y2 = bp[i * 3 + 2];
        float t = 2.0f * (n0 * y0 + n1 * y1 + n2 * y2 + off);
        y0 -= t * n0; y1 -= t * n1; y2 -= t * n2;
        float csq = y0 * y0 + y1 * y1 + y2 * y2;
        half4 q = { (_Float16)(-2.0f * y0), (_Float16)(-2.0f * y1),
                    (_Float16)(-2.0f * y2), (_Float16)csq };
        *(half4*)(qg + ((size_t)bh * NP + i) * 4) = q;
    }

    if (blockIdx.x == 0 && tid >= 192) {   // reg loss on wave 3
        const int l = tid - 192;
        float r = 0.0f;
        if (l < NB) {
            float n[NH][3];
            for (int hh = 0; hh < NH; ++hh) {
                const float* p2 = planes + (l * NH + hh) * 4;
                float a0 = p2[0], a1 = p2[1], a2 = p2[2];
                float iv = 1.0f / sqrtf(a0 * a0 + a1 * a1 + a2 * a2);
                n[hh][0] = a0 * iv; n[hh][1] = a1 * iv; n[hh][2] = a2 * iv;
            }
            float fro = 0.0f;
            for (int i = 0; i < NH; ++i)
                for (int j = 0; j < NH; ++j) {
                    float d = n[i][0] * n[j][0] + n[i][1] * n[j][1] + n[i][2] * n[j][2]
                              - (i == j ? 1.0f : 0.0f);
                    fro += d * d;
                }
            r = 25.0f * sqrtf(fro);
        }
        for (int o = 32; o; o >>= 1) r += __shfl_down(r, o);
        if (l == 0) out[0] = r;
    }
}

// SYMMETRY: the reflection is an affine isometric involution, so the
// (x vs reflected-x) distance matrix is symmetric => cham_x == cham_y;
// compute row-mins once and double.
//
// v3 = v2 structure with the register budget FIXED. v2's
// __launch_bounds__(256,6) capped VGPRs at ~85; the global-load variant
// needs ~90 plus 16-aligned tuples for the MFMA asm operands, so the
// allocator spilled the d-fragments to scratch (VGPR_Count 40, 580MB
// scratch writes, 213us). Bounds (256,5) gives a ~102-reg cap: no
// spills, and HW residency lands at 5-6 blocks/CU (grid is 6/CU), i.e.
// ~60-75% occupancy vs round-1's grid-limited 37.5%.
//
// B fragments (raw half8 = two packed columns, even col k=0..3 / odd col
// k=4..7) stream straight from the prep table in L2 via
// global_load_dwordx4 (upper half-wave reads the same lines: broadcast;
// its A-halves are zero so B k=8..15 content is annihilated). Each block
// = 64 rows; 4 waves = 2 row-groups x 2 column-halves (32 supertiles
// each). Col-halves min-combine via 512B LDS; clamp after the combine
// (max(min(a,b),0) — monotone, matches reference's clamp-before-min).
// 4-buffer load pipeline: loads ~2 lines ahead of their MFMA, min3 ~2
// lines behind.
__global__ void __launch_bounds__(BLK, 5) chamfer_mfma(const float* __restrict__ pts,
                                                       const _Float16* __restrict__ qg,
                                                       float* __restrict__ out) {
    __shared__ float rowmin[2][RPB];

    const int tid  = threadIdx.x;
    const int lane = tid & 63;
    const int wave = tid >> 6;
    const int bh   = blockIdx.y;
    const int b    = bh / NH;
    const int rw   = wave & 1;   // row group
    const int cw   = wave >> 1;  // column half
    const int h    = lane >> 5;

    const float* bp = pts + (size_t)b * NP * 3;

    // A fragments: rows = ORIGINAL points. All lanes load their row (dup
    // across halves) so rsq is shuffle-able without LDS/barrier.
    const int rlocal = rw * 32 + (lane & 31);
    const int row = blockIdx.x * RPB + rlocal;
    float a0 = bp[row * 3 + 0], a1 = bp[row * 3 + 1], a2 = bp[row * 3 + 2];
    float rsq = a0 * a0 + a1 * a1 + a2 * a2;
    half8 Aev = {0, 0, 0, 0, 0, 0, 0, 0};
    half8 Aod = {0, 0, 0, 0, 0, 0, 0, 0};
    if (lane < 32) {
        Aev[0] = (_Float16)a0; Aev[1] = (_Float16)a1;
        Aev[2] = (_Float16)a2; Aev[3] = (_Float16)1.0f;
        Aod[4] = (_Float16)a0; Aod[5] = (_Float16)a1;
        Aod[6] = (_Float16)a2; Aod[7] = (_Float16)1.0f;
    }

    // C fragment: rsq per output row (C/D: col=lane&31, row=(j&3)+8*(j>>2)+4*h)
    floatx16 crsq;
    #pragma unroll
    for (int j = 0; j < 16; ++j)
        crsq[j] = __shfl(rsq, (j & 3) + 8 * (j >> 2) + 4 * h);

    float rm[16];
    #pragma unroll
    for (int j = 0; j < 16; ++j) rm[j] = 1e30f;

    // supertile u (64 cols): lane reads cols u*64 + {2l, 2l+1} as one dwordx4
    const _Float16* bcol = qg + (size_t)bh * NP * 4 + (lane & 31) * 8;
    const int U0 = cw * 32;
    #define LD(u) (*(const half8*)(bcol + (size_t)(u) * 256))

    half8 c0 = LD(U0), c1 = LD(U0 + 1), c2 = LD(U0 + 2), c3 = LD(U0 + 3);
    floatx16 dA0, dA1, dB0, dB1;
    MFMA16(dA0, Aev, c0, crsq);  MFMA16(dA1, Aod, c0, crsq);   // st U0
    MFMA16(dB0, Aev, c1, crsq);  MFMA16(dB1, Aod, c1, crsq);   // st U0+1

    #pragma unroll 1
    for (int u = U0 + 4; u <= U0 + 28; u += 4) {
        c0 = LD(u);
        #pragma unroll
        for (int j = 0; j < 16; ++j) MIN3(rm[j], dA0[j], dA1[j]);   // st u-4
        MFMA16(dA0, Aev, c2, crsq);  MFMA16(dA1, Aod, c2, crsq);    // st u-2
        c1 = LD(u + 1);
        #pragma unroll
        for (int j = 0; j < 16; ++j) MIN3(rm[j], dB0[j], dB1[j]);   // st u-3
        MFMA16(dB0, Aev, c3, crsq);  MFMA16(dB1, Aod, c3, crsq);    // st u-1
        c2 = LD(u + 2);
        #pragma unroll
        for (int j = 0; j < 16; ++j) MIN3(rm[j], dA0[j], dA1[j]);   // st u-2
        MFMA16(dA0, Aev, c0, crsq);  MFMA16(dA1, Aod, c0, crsq);    // st u
        c3 = LD(u + 3);
        #pragma unroll
        for (int j = 0; j < 16; ++j) MIN3(rm[j], dB0[j], dB1[j]);   // st u-1
        MFMA16(dB0, Aev, c1, crsq);  MFMA16(dB1, Aod, c1, crsq);    // st u+1
    }
    {   // epilogue: st U0+30, U0+31 issue + drain
        #pragma unroll
        for (int j = 0; j < 16; ++j) MIN3(rm[j], dA0[j], dA1[j]);   // st U0+28
        MFMA16(dA0, Aev, c2, crsq);  MFMA16(dA1, Aod, c2, crsq);    // st U0+30
        #pragma unroll
        for (int j = 0; j < 16; ++j) MIN3(rm[j], dB0[j], dB1[j]);   // st U0+29
        MFMA16(dB0, Aev, c3, crsq);  MFMA16(dB1, Aod, c3, crsq);    // st U0+31
        #pragma unroll
        for (int j = 0; j < 16; ++j) MIN3(rm[j], dA0[j], dA1[j]);   // st U0+30
        #pragma unroll
        for (int j = 0; j < 16; ++j) MIN3(rm[j], dB0[j], dB1[j]);   // st U0+31
    }
    #undef LD

    // min across the 32 lanes sharing each row (within this col-half)
    #pragma unroll
    for (int j = 0; j < 16; ++j) {
        float v = rm[j];
        v = fminf(v, __shfl_xor(v, 1));
        v = fminf(v, __shfl_xor(v, 2));
        v = fminf(v, __shfl_xor(v, 4));
        v = fminf(v, __shfl_xor(v, 8));
        v = fminf(v, __shfl_xor(v, 16));
        rm[j] = v;
    }

    // publish per-row partial mins (one lane per 32-group; constant j idx
    // only — runtime-indexing rm[] would spill to scratch)
    if ((lane & 31) == 0) {
        #pragma unroll
        for (int j = 0; j < 16; ++j)
            rowmin[cw][rw * 32 + (j & 3) + 8 * (j >> 2) + 4 * h] = rm[j];
    }
    __syncthreads();

    // combine col-halves, clamp, sum 64 rows, one atomic per block
    if (tid < RPB) {
        float v = fmaxf(fminf(rowmin[0][tid], rowmin[1][tid]), 0.0f);
        #pragma unroll
        for (int o = 32; o; o >>= 1) v += __shfl_down(v, o);
        if (tid == 0) atomicAdd(out, v * (2.0f / (float)(NB * NP)));
    }
}

extern "C" void kernel_launch(void* const* d_in, const int* in_sizes, int n_in,
                              void* d_out, int out_size, void* d_ws, size_t ws_size,
                              hipStream_t stream) {
    const float* planes = (const float*)d_in[0];  // (8,3,4) fp32
    const float* pts    = (const float*)d_in[1];  // (8,4096,3) fp32
    float* out          = (float*)d_out;
    _Float16* qg        = (_Float16*)d_ws;        // needs 24*4096*8 = 768 KB

    prep_kernel<<<96, 256, 0, stream>>>(pts, planes, qg, out);

    dim3 grid(ROWBLKS, NBH);
    chamfer_mfma<<<grid, BLK, 0, stream>>>(pts, qg, out);
}

// Round 4
// 86.731 us; speedup vs baseline: 3.0760x; 2.2362x over previous
//
#include <hip/hip_runtime.h>
#include <math.h>

#define NB 8
#define NH 3
#define NBH 24
#define NP 4096
#define BLK 256
#define RPB 64             // rows per block (2 row-waves x 32; 2 col-half waves)
#define ROWBLKS (NP / RPB) // 64

typedef _Float16 half4 __attribute__((ext_vector_type(4)));
typedef _Float16 half8 __attribute__((ext_vector_type(8)));
typedef float floatx16 __attribute__((ext_vector_type(16)));

// Forced v_min3_f32 (3-input min; no -ffast-math so compiler won't fuse).
#define MIN3(r, a, b) asm("v_min3_f32 %0, %0, %1, %2" : "+v"(r) : "v"(a), "v"(b))

// Native gfx950 x16 MFMA via inline asm, all-VGPR.
#define MFMA16(d, a, bb, c) \
    asm("v_mfma_f32_32x32x16_f16 %0, %1, %2, %3" : "=&v"(d) : "v"(a), "v"(bb), "v"(c))

// Prep: for each (b,h), reflect all 4096 points and pack per-column
// [-2c0,-2c1,-2c2,csq] as 4xf16 into the workspace (24 x 32KB = 768KB,
// L2-resident). 384 blocks, 1 point/thread. Block 0 wave 3 also computes
// the regularizer and plain-stores out[0] (chamfer atomicAdds after).
__global__ void __launch_bounds__(256) prep_kernel(const float* __restrict__ pts,
                                                   const float* __restrict__ planes,
                                                   _Float16* __restrict__ qg,
                                                   float* __restrict__ out) {
    const int tid = threadIdx.x;
    const int bh  = blockIdx.x >> 4;      // 384 blocks, 16 per (b,h)
    const int b   = bh / NH;

    const float* pl = planes + bh * 4;
    float n0 = pl[0], n1 = pl[1], n2 = pl[2], off = pl[3];
    float inv = 1.0f / sqrtf(n0 * n0 + n1 * n1 + n2 * n2);
    n0 *= inv; n1 *= inv; n2 *= inv;

    const float* bp = pts + (size_t)b * NP * 3;
    const int i = (blockIdx.x & 15) * 256 + tid;
    {
        float y0 = bp[i * 3 + 0], y1 = bp[i * 3 + 1], y2 = bp[i * 3 + 2];
        float t = 2.0f * (n0 * y0 + n1 * y1 + n2 * y2 + off);
        y0 -= t * n0; y1 -= t * n1; y2 -= t * n2;
        float csq = y0 * y0 + y1 * y1 + y2 * y2;
        half4 q = { (_Float16)(-2.0f * y0), (_Float16)(-2.0f * y1),
                    (_Float16)(-2.0f * y2), (_Float16)csq };
        *(half4*)(qg + ((size_t)bh * NP + i) * 4) = q;
    }

    if (blockIdx.x == 0 && tid >= 192) {   // reg loss on wave 3
        const int l = tid - 192;
        float r = 0.0f;
        if (l < NB) {
            float n[NH][3];
            for (int hh = 0; hh < NH; ++hh) {
                const float* p2 = planes + (l * NH + hh) * 4;
                float a0 = p2[0], a1 = p2[1], a2 = p2[2];
                float iv = 1.0f / sqrtf(a0 * a0 + a1 * a1 + a2 * a2);
                n[hh][0] = a0 * iv; n[hh][1] = a1 * iv; n[hh][2] = a2 * iv;
            }
            float fro = 0.0f;
            for (int i2 = 0; i2 < NH; ++i2)
                for (int j = 0; j < NH; ++j) {
                    float d = n[i2][0] * n[j][0] + n[i2][1] * n[j][1] + n[i2][2] * n[j][2]
                              - (i2 == j ? 1.0f : 0.0f);
                    fro += d * d;
                }
            r = 25.0f * sqrtf(fro);
        }
        for (int o = 32; o; o >>= 1) r += __shfl_down(r, o);
        if (l == 0) out[0] = r;
    }
}

// SYMMETRY: reflection is an affine isometric involution => the distance
// matrix is symmetric => cham_x == cham_y; compute row-mins once, double.
//
// v4 = v3 with the live-register set actually SHRUNK instead of the cap
// squeezed: ONE d-pair (dA0/dA1) instead of two (-32 VGPRs) puts the
// live set at ~98 < 102, so 5 waves/SIMD fit naturally. Bounds (256,4)
// (cap 128) leaves ~30 regs of allocator slack => guaranteed no spill
// (v2/v3 lesson: forcing the cap below the live set = 300+MB scratch).
// Lost ILP (min3 waits ~30cyc on MFMA latency once per supertile) is
// hidden by TLP: 4-5 waves/SIMD vs v1's 3.
//
// B fragments (raw half8 = two packed columns, even col k=0..3 / odd col
// k=4..7) stream from the prep table in L2 via global_load_dwordx4
// (upper half-wave reads the same lines: broadcast; its A-halves are
// zero so B k=8..15 content is annihilated). Block = 64 rows; 4 waves =
// 2 row-groups x 2 column-halves (32 supertiles each). Col-halves
// min-combine via 512B LDS; clamp after combine (max(min,0) — monotone).
// c0..c3 prefetch runs 4 stiles (~350cyc) ahead of use => L2 latency
// (~200-300cyc) covered.
__global__ void __launch_bounds__(BLK, 4) chamfer_mfma(const float* __restrict__ pts,
                                                       const _Float16* __restrict__ qg,
                                                       float* __restrict__ out) {
    __shared__ float rowmin[2][RPB];

    const int tid  = threadIdx.x;
    const int lane = tid & 63;
    const int wave = tid >> 6;
    const int bh   = blockIdx.y;
    const int b    = bh / NH;
    const int rw   = wave & 1;   // row group
    const int cw   = wave >> 1;  // column half
    const int h    = lane >> 5;

    const float* bp = pts + (size_t)b * NP * 3;

    // A fragments: rows = ORIGINAL points. All lanes load their row (dup
    // across halves) so rsq is shuffle-able without LDS/barrier.
    const int rlocal = rw * 32 + (lane & 31);
    const int row = blockIdx.x * RPB + rlocal;
    float a0 = bp[row * 3 + 0], a1 = bp[row * 3 + 1], a2 = bp[row * 3 + 2];
    float rsq = a0 * a0 + a1 * a1 + a2 * a2;
    half8 Aev = {0, 0, 0, 0, 0, 0, 0, 0};
    half8 Aod = {0, 0, 0, 0, 0, 0, 0, 0};
    if (lane < 32) {
        Aev[0] = (_Float16)a0; Aev[1] = (_Float16)a1;
        Aev[2] = (_Float16)a2; Aev[3] = (_Float16)1.0f;
        Aod[4] = (_Float16)a0; Aod[5] = (_Float16)a1;
        Aod[6] = (_Float16)a2; Aod[7] = (_Float16)1.0f;
    }

    // C fragment: rsq per output row (C/D: col=lane&31, row=(j&3)+8*(j>>2)+4*h)
    floatx16 crsq;
    #pragma unroll
    for (int j = 0; j < 16; ++j)
        crsq[j] = __shfl(rsq, (j & 3) + 8 * (j >> 2) + 4 * h);

    float rm[16];
    #pragma unroll
    for (int j = 0; j < 16; ++j) rm[j] = 1e30f;

    // supertile u (64 cols): lane reads cols u*64 + {2l, 2l+1} as one dwordx4
    const _Float16* bcol = qg + (size_t)bh * NP * 4 + (lane & 31) * 8;
    const int U0 = cw * 32;
    #define LD(u) (*(const half8*)(bcol + (size_t)(u) * 256))

    half8 c0 = LD(U0), c1 = LD(U0 + 1), c2 = LD(U0 + 2), c3 = LD(U0 + 3);
    floatx16 dA0, dA1;
    MFMA16(dA0, Aev, c0, crsq);  MFMA16(dA1, Aod, c0, crsq);   // stile U0

    // One d-pair pipeline: each iter consumes stiles u..u+3, issues u+1..u+4.
    #pragma unroll 1
    for (int u = U0; u < U0 + 28; u += 4) {
        c0 = LD(u + 4);
        #pragma unroll
        for (int j = 0; j < 16; ++j) MIN3(rm[j], dA0[j], dA1[j]);   // st u
        MFMA16(dA0, Aev, c1, crsq);  MFMA16(dA1, Aod, c1, crsq);    // st u+1
        c1 = LD(u + 5);
        #pragma unroll
        for (int j = 0; j < 16; ++j) MIN3(rm[j], dA0[j], dA1[j]);   // st u+1
        MFMA16(dA0, Aev, c2, crsq);  MFMA16(dA1, Aod, c2, crsq);    // st u+2
        c2 = LD(u + 6);
        #pragma unroll
        for (int j = 0; j < 16; ++j) MIN3(rm[j], dA0[j], dA1[j]);   // st u+2
        MFMA16(dA0, Aev, c3, crsq);  MFMA16(dA1, Aod, c3, crsq);    // st u+3
        c3 = LD(u + 7);
        #pragma unroll
        for (int j = 0; j < 16; ++j) MIN3(rm[j], dA0[j], dA1[j]);   // st u+3
        MFMA16(dA0, Aev, c0, crsq);  MFMA16(dA1, Aod, c0, crsq);    // st u+4
    }
    {   // epilogue: dA holds st U0+28; c1,c2,c3 hold stiles 29,30,31
        #pragma unroll
        for (int j = 0; j < 16; ++j) MIN3(rm[j], dA0[j], dA1[j]);   // st U0+28
        MFMA16(dA0, Aev, c1, crsq);  MFMA16(dA1, Aod, c1, crsq);
        #pragma unroll
        for (int j = 0; j < 16; ++j) MIN3(rm[j], dA0[j], dA1[j]);   // st U0+29
        MFMA16(dA0, Aev, c2, crsq);  MFMA16(dA1, Aod, c2, crsq);
        #pragma unroll
        for (int j = 0; j < 16; ++j) MIN3(rm[j], dA0[j], dA1[j]);   // st U0+30
        MFMA16(dA0, Aev, c3, crsq);  MFMA16(dA1, Aod, c3, crsq);
        #pragma unroll
        for (int j = 0; j < 16; ++j) MIN3(rm[j], dA0[j], dA1[j]);   // st U0+31
    }
    #undef LD

    // min across the 32 lanes sharing each row (within this col-half)
    #pragma unroll
    for (int j = 0; j < 16; ++j) {
        float v = rm[j];
        v = fminf(v, __shfl_xor(v, 1));
        v = fminf(v, __shfl_xor(v, 2));
        v = fminf(v, __shfl_xor(v, 4));
        v = fminf(v, __shfl_xor(v, 8));
        v = fminf(v, __shfl_xor(v, 16));
        rm[j] = v;
    }

    // publish per-row partial mins (one lane per 32-group; constant j idx
    // only — runtime-indexing rm[] would spill to scratch)
    if ((lane & 31) == 0) {
        #pragma unroll
        for (int j = 0; j < 16; ++j)
            rowmin[cw][rw * 32 + (j & 3) + 8 * (j >> 2) + 4 * h] = rm[j];
    }
    __syncthreads();

    // combine col-halves, clamp, sum 64 rows, one atomic per block
    if (tid < RPB) {
        float v = fmaxf(fminf(rowmin[0][tid], rowmin[1][tid]), 0.0f);
        #pragma unroll
        for (int o = 32; o; o >>= 1) v += __shfl_down(v, o);
        if (tid == 0) atomicAdd(out, v * (2.0f / (float)(NB * NP)));
    }
}

extern "C" void kernel_launch(void* const* d_in, const int* in_sizes, int n_in,
                              void* d_out, int out_size, void* d_ws, size_t ws_size,
                              hipStream_t stream) {
    const float* planes = (const float*)d_in[0];  // (8,3,4) fp32
    const float* pts    = (const float*)d_in[1];  // (8,4096,3) fp32
    float* out          = (float*)d_out;
    _Float16* qg        = (_Float16*)d_ws;        // needs 24*4096*8 = 768 KB

    prep_kernel<<<384, 256, 0, stream>>>(pts, planes, qg, out);

    dim3 grid(ROWBLKS, NBH);
    chamfer_mfma<<<grid, BLK, 0, stream>>>(pts, qg, out);
}